// Round 1
// baseline (947.850 us; speedup 1.0000x reference)
//
#include <hip/hip_runtime.h>
#include <math.h>

#define TOKS 8192
#define HD   2048
#define ID   1408
#define NE   8
#define N13  2816

typedef int v4i __attribute__((ext_vector_type(4)));

// ---------------- gating + dynamic x quant + routing lists ----------------
__global__ __launch_bounds__(256) void gate_quant_kernel(
    const float* __restrict__ x, const float* __restrict__ gw,
    signed char* __restrict__ xq, float* __restrict__ xs,
    float* __restrict__ gates, int* __restrict__ counts, int* __restrict__ lists)
{
    const int t = blockIdx.x;
    const int tid = threadIdx.x;
    const float* xr = x + (size_t)t * HD + tid * 8;
    const float4 xa = *(const float4*)(xr);
    const float4 xb = *(const float4*)(xr + 4);
    float acc[NE];
#pragma unroll
    for (int e = 0; e < NE; ++e) {
        const float* wr = gw + e * HD + tid * 8;
        float4 wa = *(const float4*)(wr);
        float4 wb = *(const float4*)(wr + 4);
        acc[e] = xa.x*wa.x + xa.y*wa.y + xa.z*wa.z + xa.w*wa.w +
                 xb.x*wb.x + xb.y*wb.y + xb.z*wb.z + xb.w*wb.w;
    }
    float am = fmaxf(fmaxf(fmaxf(fabsf(xa.x), fabsf(xa.y)), fmaxf(fabsf(xa.z), fabsf(xa.w))),
                     fmaxf(fmaxf(fabsf(xb.x), fabsf(xb.y)), fmaxf(fabsf(xb.z), fabsf(xb.w))));
#pragma unroll
    for (int off = 1; off < 64; off <<= 1) {
#pragma unroll
        for (int e = 0; e < NE; ++e) acc[e] += __shfl_xor(acc[e], off);
        am = fmaxf(am, __shfl_xor(am, off));
    }
    __shared__ float red[4][9];
    __shared__ float sbc;
    const int wv = tid >> 6;
    if ((tid & 63) == 0) {
#pragma unroll
        for (int e = 0; e < NE; ++e) red[wv][e] = acc[e];
        red[wv][8] = am;
    }
    __syncthreads();
    if (tid == 0) {
        float l[NE];
#pragma unroll
        for (int e = 0; e < NE; ++e) l[e] = red[0][e] + red[1][e] + red[2][e] + red[3][e];
        float amx = fmaxf(fmaxf(red[0][8], red[1][8]), fmaxf(red[2][8], red[3][8]));
        int e0 = 0;
#pragma unroll
        for (int e = 1; e < NE; ++e) if (l[e] > l[e0]) e0 = e;
        int e1 = (e0 == 0) ? 1 : 0;
#pragma unroll
        for (int e = 0; e < NE; ++e) if (e != e0 && l[e] > l[e1]) e1 = e;
        // top-2 softmax renormalized == 2-way softmax
        const float d = expf(l[e1] - l[e0]);
        gates[2*t]     = 1.0f / (1.0f + d);
        gates[2*t + 1] = d / (1.0f + d);
        const int p0 = atomicAdd(&counts[e0], 1); lists[e0*TOKS + p0] = 2*t;
        const int p1 = atomicAdd(&counts[e1], 1); lists[e1*TOKS + p1] = 2*t + 1;
        const float s = fmaxf(amx / 127.0f, 1e-8f);
        xs[t] = s;
        sbc = s;
    }
    __syncthreads();
    const float s = sbc;
    const float v[8] = {xa.x, xa.y, xa.z, xa.w, xb.x, xb.y, xb.z, xb.w};
    unsigned int lo = 0, hi = 0;
#pragma unroll
    for (int i = 0; i < 4; ++i) {
        int q = (int)fminf(fmaxf(rintf(v[i] / s), -127.f), 127.f);
        lo |= ((unsigned)(q & 0xff)) << (8 * i);
    }
#pragma unroll
    for (int i = 0; i < 4; ++i) {
        int q = (int)fminf(fmaxf(rintf(v[4 + i] / s), -127.f), 127.f);
        hi |= ((unsigned)(q & 0xff)) << (8 * i);
    }
    int2 pk; pk.x = (int)lo; pk.y = (int)hi;
    *(int2*)(xq + (size_t)t * HD + tid * 8) = pk;
}

// ---------------- weight conversion int32 -> int8 ----------------
// w13: interleave rows so SwiGLU pair (gate i, up i) sits at columns
// n' = (i>>4)*32 + g*16 + (i&15)  -> pair is (same lane, adjacent 16-col MFMA tiles)
__global__ __launch_bounds__(256) void convert_w13_kernel(
    const int* __restrict__ wq, signed char* __restrict__ w8)
{
    const unsigned idx = blockIdx.x * 256u + threadIdx.x;  // one per 4 k-elements
    const unsigned kq = idx & 511u;        // k/4 (HD/4 = 512)
    const unsigned rowq = idx >> 9;        // e*N13 + n'
    const unsigned np = rowq % 2816u;
    const unsigned e = rowq / 2816u;
    const unsigned inrow = ((np >> 4) & 1u) * 1408u + (np >> 5) * 16u + (np & 15u);
    const int4 vv = *(const int4*)(wq + (size_t)(e * 2816u + inrow) * 2048u + kq * 4u);
    char4 c;
    c.x = (signed char)vv.x; c.y = (signed char)vv.y;
    c.z = (signed char)vv.z; c.w = (signed char)vv.w;
    *(char4*)(w8 + (size_t)rowq * 2048u + kq * 4u) = c;
}

__global__ __launch_bounds__(256) void convert_w2_kernel(
    const int* __restrict__ wq, signed char* __restrict__ w8)
{
    const size_t idx = (size_t)blockIdx.x * 256 + threadIdx.x;
    const int4 vv = *(const int4*)(wq + idx * 4);
    char4 c;
    c.x = (signed char)vv.x; c.y = (signed char)vv.y;
    c.z = (signed char)vv.z; c.w = (signed char)vv.w;
    *(char4*)(w8 + idx * 4) = c;
}

// ---------------- out = shared_output ----------------
__global__ __launch_bounds__(256) void copy_out_kernel(
    const float* __restrict__ src, float* __restrict__ dst)
{
    const size_t idx = (size_t)blockIdx.x * 256 + threadIdx.x;
    ((float4*)dst)[idx] = ((const float4*)src)[idx];
}

// ---------------- fc1: grouped int8 GEMM + SwiGLU + row-absmax ----------------
__global__ __launch_bounds__(256, 2) void fc1_kernel(
    const signed char* __restrict__ xq, const signed char* __restrict__ w13_8,
    const float* __restrict__ xs, const float* __restrict__ w13s,
    const int* __restrict__ counts, const int* __restrict__ lists,
    float* __restrict__ a_buf, unsigned int* __restrict__ amax)
{
    const int e = blockIdx.z;
    const int n_e = counts[e];
    const int m0 = blockIdx.y * 128;
    if (m0 >= n_e) return;
    const int n0 = blockIdx.x * 128;
    const int* list = lists + e * TOKS;
    const signed char* B = w13_8 + (size_t)e * N13 * HD;

    __shared__ signed char lsA[128 * 80];  // stride 80: frag reads 2-way (free)
    __shared__ signed char lsB[128 * 80];

    const int tid = threadIdx.x;
    const int srow = tid >> 1, shalf = tid & 1;
    const int aidx = m0 + srow;
    const int aslot = (aidx < n_e) ? list[aidx] : 0;
    const signed char* Aptr = xq + (size_t)(aslot >> 1) * HD + shalf * 32;
    const signed char* Bptr = B + (size_t)(n0 + srow) * HD + shalf * 32;
    signed char* wA = lsA + srow * 80 + shalf * 32;
    signed char* wB = lsB + srow * 80 + shalf * 32;

    const int lane = tid & 63;
    const int wv = tid >> 6;
    const int quad = lane >> 4, jj = lane & 15;
    const int wm = (wv >> 1) * 64, wn = (wv & 1) * 64;

    const v4i zero = {0, 0, 0, 0};
    v4i acc[4][4];
#pragma unroll
    for (int a = 0; a < 4; ++a)
#pragma unroll
        for (int b = 0; b < 4; ++b) acc[a][b] = zero;

    for (int kc = 0; kc < 32; ++kc) {
        const int k0 = kc * 64;
        const int4 a0 = *(const int4*)(Aptr + k0);
        const int4 a1 = *(const int4*)(Aptr + k0 + 16);
        const int4 b0 = *(const int4*)(Bptr + k0);
        const int4 b1 = *(const int4*)(Bptr + k0 + 16);
        __syncthreads();
        *(int4*)(wA) = a0;
        *(int4*)(wA + 16) = a1;
        *(int4*)(wB) = b0;
        *(int4*)(wB + 16) = b1;
        __syncthreads();
        v4i af[4], bf[4];
#pragma unroll
        for (int mi = 0; mi < 4; ++mi)
            af[mi] = *(const v4i*)(lsA + (wm + mi * 16 + jj) * 80 + quad * 16);
#pragma unroll
        for (int ni = 0; ni < 4; ++ni)
            bf[ni] = *(const v4i*)(lsB + (wn + ni * 16 + jj) * 80 + quad * 16);
#pragma unroll
        for (int mi = 0; mi < 4; ++mi)
#pragma unroll
            for (int ni = 0; ni < 4; ++ni)
                acc[mi][ni] = __builtin_amdgcn_mfma_i32_16x16x64_i8(af[mi], bf[ni], acc[mi][ni], 0, 0, 0);
    }

    // epilogue: dequant, SwiGLU (pairs are ni even/odd, same lane), write a + absmax
    const float* s13e = w13s + e * N13;
    const int qbase = (n0 + wn) >> 5;
#pragma unroll
    for (int mi = 0; mi < 4; ++mi) {
#pragma unroll
        for (int r = 0; r < 4; ++r) {
            const int idx = m0 + wm + mi * 16 + quad * 4 + r;
            const bool valid = (idx < n_e);
            int slot = 0; float xsv = 0.f;
            if (valid) { slot = list[idx]; xsv = xs[slot >> 1]; }
            float rowmax = 0.f;
            float avals[2];
#pragma unroll
            for (int p = 0; p < 2; ++p) {
                const int q = qbase + p;
                const float sg = s13e[q * 16 + jj];
                const float su = s13e[ID + q * 16 + jj];
                const float hg = (float)acc[mi][2 * p][r] * xsv * sg;
                const float hu = (float)acc[mi][2 * p + 1][r] * xsv * su;
                const float av = hg / (1.0f + expf(-hg)) * hu;  // silu(gate)*up
                avals[p] = av;
                rowmax = fmaxf(rowmax, fabsf(av));
            }
            // reduce across the 16 j-lanes of this row (validity uniform over j)
            rowmax = fmaxf(rowmax, __shfl_xor(rowmax, 1));
            rowmax = fmaxf(rowmax, __shfl_xor(rowmax, 2));
            rowmax = fmaxf(rowmax, __shfl_xor(rowmax, 4));
            rowmax = fmaxf(rowmax, __shfl_xor(rowmax, 8));
            if (valid) {
                float* arow = a_buf + (size_t)slot * ID;
#pragma unroll
                for (int p = 0; p < 2; ++p) arow[(qbase + p) * 16 + jj] = avals[p];
                if (jj == 0) atomicMax(amax + slot, __float_as_uint(rowmax));
            }
        }
    }
}

// ---------------- requant: a fp32 -> aq int8 with per-row scale ----------------
__global__ __launch_bounds__(256) void requant_kernel(
    const float* __restrict__ a_buf, const unsigned int* __restrict__ amax,
    float* __restrict__ a_s, signed char* __restrict__ aq)
{
    const int row = blockIdx.x;
    const float am = __uint_as_float(amax[row]);
    const float s = fmaxf(am / 127.0f, 1e-8f);
    if (threadIdx.x == 0) a_s[row] = s;
    const float* ar = a_buf + (size_t)row * ID;
    signed char* qr = aq + (size_t)row * ID;
    for (int c = threadIdx.x; c < ID / 4; c += 256) {
        const float4 v = *(const float4*)(ar + c * 4);
        char4 o;
        o.x = (signed char)(int)fminf(fmaxf(rintf(v.x / s), -127.f), 127.f);
        o.y = (signed char)(int)fminf(fmaxf(rintf(v.y / s), -127.f), 127.f);
        o.z = (signed char)(int)fminf(fmaxf(rintf(v.z / s), -127.f), 127.f);
        o.w = (signed char)(int)fminf(fmaxf(rintf(v.w / s), -127.f), 127.f);
        *(char4*)(qr + c * 4) = o;
    }
}

// ---------------- fc2: grouped int8 GEMM + weighted atomic combine ----------------
__global__ __launch_bounds__(256, 2) void fc2_kernel(
    const signed char* __restrict__ aq, const signed char* __restrict__ w2_8,
    const float* __restrict__ a_s, const float* __restrict__ w2s,
    const float* __restrict__ gates,
    const int* __restrict__ counts, const int* __restrict__ lists,
    float* __restrict__ out)
{
    const int e = blockIdx.z;
    const int n_e = counts[e];
    const int m0 = blockIdx.y * 128;
    if (m0 >= n_e) return;
    const int n0 = blockIdx.x * 128;
    const int* list = lists + e * TOKS;
    const signed char* B = w2_8 + (size_t)e * HD * ID;

    __shared__ signed char lsA[128 * 80];
    __shared__ signed char lsB[128 * 80];

    const int tid = threadIdx.x;
    const int srow = tid >> 1, shalf = tid & 1;
    const int aidx = m0 + srow;
    const int aslot = (aidx < n_e) ? list[aidx] : 0;
    const signed char* Aptr = aq + (size_t)aslot * ID + shalf * 32;
    const signed char* Bptr = B + (size_t)(n0 + srow) * ID + shalf * 32;
    signed char* wA = lsA + srow * 80 + shalf * 32;
    signed char* wB = lsB + srow * 80 + shalf * 32;

    const int lane = tid & 63;
    const int wv = tid >> 6;
    const int quad = lane >> 4, jj = lane & 15;
    const int wm = (wv >> 1) * 64, wn = (wv & 1) * 64;

    const v4i zero = {0, 0, 0, 0};
    v4i acc[4][4];
#pragma unroll
    for (int a = 0; a < 4; ++a)
#pragma unroll
        for (int b = 0; b < 4; ++b) acc[a][b] = zero;

    for (int kc = 0; kc < 22; ++kc) {  // K = 1408 = 22*64
        const int k0 = kc * 64;
        const int4 a0 = *(const int4*)(Aptr + k0);
        const int4 a1 = *(const int4*)(Aptr + k0 + 16);
        const int4 b0 = *(const int4*)(Bptr + k0);
        const int4 b1 = *(const int4*)(Bptr + k0 + 16);
        __syncthreads();
        *(int4*)(wA) = a0;
        *(int4*)(wA + 16) = a1;
        *(int4*)(wB) = b0;
        *(int4*)(wB + 16) = b1;
        __syncthreads();
        v4i af[4], bf[4];
#pragma unroll
        for (int mi = 0; mi < 4; ++mi)
            af[mi] = *(const v4i*)(lsA + (wm + mi * 16 + jj) * 80 + quad * 16);
#pragma unroll
        for (int ni = 0; ni < 4; ++ni)
            bf[ni] = *(const v4i*)(lsB + (wn + ni * 16 + jj) * 80 + quad * 16);
#pragma unroll
        for (int mi = 0; mi < 4; ++mi)
#pragma unroll
            for (int ni = 0; ni < 4; ++ni)
                acc[mi][ni] = __builtin_amdgcn_mfma_i32_16x16x64_i8(af[mi], bf[ni], acc[mi][ni], 0, 0, 0);
    }

    const float* s2e = w2s + e * HD;
    float s2v[4];
#pragma unroll
    for (int ni = 0; ni < 4; ++ni) s2v[ni] = s2e[n0 + wn + ni * 16 + jj];
#pragma unroll
    for (int mi = 0; mi < 4; ++mi) {
#pragma unroll
        for (int r = 0; r < 4; ++r) {
            const int idx = m0 + wm + mi * 16 + quad * 4 + r;
            if (idx >= n_e) continue;
            const int slot = list[idx];
            const float coef = a_s[slot] * gates[slot];
            float* orow = out + (size_t)(slot >> 1) * HD + n0 + wn;
#pragma unroll
            for (int ni = 0; ni < 4; ++ni)
                atomicAdd(orow + ni * 16 + jj, (float)acc[mi][ni][r] * coef * s2v[ni]);
        }
    }
}

extern "C" void kernel_launch(void* const* d_in, const int* in_sizes, int n_in,
                              void* d_out, int out_size, void* d_ws, size_t ws_size,
                              hipStream_t stream)
{
    const float* x      = (const float*)d_in[0];
    const float* gw     = (const float*)d_in[1];
    const int*   w13q   = (const int*)d_in[2];
    const float* w13s   = (const float*)d_in[3];
    const int*   w2q    = (const int*)d_in[4];
    const float* w2s    = (const float*)d_in[5];
    const float* shared = (const float*)d_in[6];
    float* out = (float*)d_out;
    char* ws = (char*)d_ws;

    constexpr size_t SZ_W13 = (size_t)NE * N13 * HD;   // 46,137,344
    constexpr size_t SZ_W2  = (size_t)NE * HD * ID;    // 23,068,672
    constexpr size_t SZ_XQ  = (size_t)TOKS * HD;       // 16,777,216
    constexpr size_t SZ_AQ  = (size_t)2 * TOKS * ID;   // 23,068,672
    constexpr size_t SZ_A   = SZ_AQ * 4;               // 92,274,688
    constexpr size_t OFF_W13 = 0;
    constexpr size_t OFF_W2  = OFF_W13 + SZ_W13;
    constexpr size_t OFF_XQ  = OFF_W2 + SZ_W2;
    constexpr size_t OFF_AQ  = OFF_XQ + SZ_XQ;
    constexpr size_t OFF_A   = OFF_AQ + SZ_AQ;
    constexpr size_t OFF_XS  = OFF_A + SZ_A;
    constexpr size_t OFF_AS  = OFF_XS + 65536;
    constexpr size_t OFF_G   = OFF_AS + 65536;
    constexpr size_t OFF_AM  = OFF_G + 65536;
    constexpr size_t OFF_CNT = OFF_AM + 65536;
    constexpr size_t OFF_LST = OFF_CNT + 256;   // lists: 8*8192*4 bytes

    signed char* w13_8 = (signed char*)(ws + OFF_W13);
    signed char* w2_8  = (signed char*)(ws + OFF_W2);
    signed char* xq    = (signed char*)(ws + OFF_XQ);
    signed char* aqb   = (signed char*)(ws + OFF_AQ);
    float* a_buf = (float*)(ws + OFF_A);
    float* xs    = (float*)(ws + OFF_XS);
    float* a_s   = (float*)(ws + OFF_AS);
    float* gates = (float*)(ws + OFF_G);
    unsigned int* amax = (unsigned int*)(ws + OFF_AM);
    int* counts = (int*)(ws + OFF_CNT);
    int* lists  = (int*)(ws + OFF_LST);

    hipMemsetAsync(counts, 0, 256, stream);
    hipMemsetAsync(amax, 0, 65536, stream);

    gate_quant_kernel<<<TOKS, 256, 0, stream>>>(x, gw, xq, xs, gates, counts, lists);
    convert_w13_kernel<<<(NE * N13 * (HD / 4)) / 256, 256, 0, stream>>>(w13q, w13_8);
    convert_w2_kernel<<<(NE * HD * (ID / 4)) / 256, 256, 0, stream>>>(w2q, w2_8);
    copy_out_kernel<<<(TOKS * HD / 4) / 256, 256, 0, stream>>>(shared, out);
    fc1_kernel<<<dim3(N13 / 128, 64, NE), 256, 0, stream>>>(
        xq, w13_8, xs, w13s, counts, lists, a_buf, amax);
    requant_kernel<<<2 * TOKS, 256, 0, stream>>>(a_buf, amax, a_s, aqb);
    fc2_kernel<<<dim3(HD / 128, 64, NE), 256, 0, stream>>>(
        aqb, w2_8, a_s, w2s, gates, counts, lists, out);
}

// Round 2
// 920.834 us; speedup vs baseline: 1.0293x; 1.0293x over previous
//
#include <hip/hip_runtime.h>
#include <hip/hip_bf16.h>
#include <math.h>

#define TOKS 8192
#define HD   2048
#define ID   1408
#define NE   8
#define N13  2816

typedef int v4i __attribute__((ext_vector_type(4)));

__device__ __forceinline__ void async_copy16(const signed char* g, signed char* l) {
    __builtin_amdgcn_global_load_lds(
        (const __attribute__((address_space(1))) void*)g,
        (__attribute__((address_space(3))) void*)l, 16, 0, 0);
}

// ---------------- gating + dynamic x quant + routing lists ----------------
__global__ __launch_bounds__(256) void gate_quant_kernel(
    const float* __restrict__ x, const float* __restrict__ gw,
    signed char* __restrict__ xq, float* __restrict__ xs,
    float* __restrict__ gates, int* __restrict__ counts, int* __restrict__ lists)
{
    const int t = blockIdx.x;
    const int tid = threadIdx.x;
    const float* xr = x + (size_t)t * HD + tid * 8;
    const float4 xa = *(const float4*)(xr);
    const float4 xb = *(const float4*)(xr + 4);
    float acc[NE];
#pragma unroll
    for (int e = 0; e < NE; ++e) {
        const float* wr = gw + e * HD + tid * 8;
        float4 wa = *(const float4*)(wr);
        float4 wb = *(const float4*)(wr + 4);
        acc[e] = xa.x*wa.x + xa.y*wa.y + xa.z*wa.z + xa.w*wa.w +
                 xb.x*wb.x + xb.y*wb.y + xb.z*wb.z + xb.w*wb.w;
    }
    float am = fmaxf(fmaxf(fmaxf(fabsf(xa.x), fabsf(xa.y)), fmaxf(fabsf(xa.z), fabsf(xa.w))),
                     fmaxf(fmaxf(fabsf(xb.x), fabsf(xb.y)), fmaxf(fabsf(xb.z), fabsf(xb.w))));
#pragma unroll
    for (int off = 1; off < 64; off <<= 1) {
#pragma unroll
        for (int e = 0; e < NE; ++e) acc[e] += __shfl_xor(acc[e], off);
        am = fmaxf(am, __shfl_xor(am, off));
    }
    __shared__ float red[4][9];
    __shared__ float sbc;
    const int wv = tid >> 6;
    if ((tid & 63) == 0) {
#pragma unroll
        for (int e = 0; e < NE; ++e) red[wv][e] = acc[e];
        red[wv][8] = am;
    }
    __syncthreads();
    if (tid == 0) {
        float l[NE];
#pragma unroll
        for (int e = 0; e < NE; ++e) l[e] = red[0][e] + red[1][e] + red[2][e] + red[3][e];
        float amx = fmaxf(fmaxf(red[0][8], red[1][8]), fmaxf(red[2][8], red[3][8]));
        int e0 = 0;
#pragma unroll
        for (int e = 1; e < NE; ++e) if (l[e] > l[e0]) e0 = e;
        int e1 = (e0 == 0) ? 1 : 0;
#pragma unroll
        for (int e = 0; e < NE; ++e) if (e != e0 && l[e] > l[e1]) e1 = e;
        const float d = expf(l[e1] - l[e0]);
        gates[2*t]     = 1.0f / (1.0f + d);
        gates[2*t + 1] = d / (1.0f + d);
        const int p0 = atomicAdd(&counts[e0], 1); lists[e0*TOKS + p0] = 2*t;
        const int p1 = atomicAdd(&counts[e1], 1); lists[e1*TOKS + p1] = 2*t + 1;
        const float s = fmaxf(amx / 127.0f, 1e-8f);
        xs[t] = s;
        sbc = s;
    }
    __syncthreads();
    const float s = sbc;
    const float v[8] = {xa.x, xa.y, xa.z, xa.w, xb.x, xb.y, xb.z, xb.w};
    unsigned int lo = 0, hi = 0;
#pragma unroll
    for (int i = 0; i < 4; ++i) {
        int q = (int)fminf(fmaxf(rintf(v[i] / s), -127.f), 127.f);
        lo |= ((unsigned)(q & 0xff)) << (8 * i);
    }
#pragma unroll
    for (int i = 0; i < 4; ++i) {
        int q = (int)fminf(fmaxf(rintf(v[4 + i] / s), -127.f), 127.f);
        hi |= ((unsigned)(q & 0xff)) << (8 * i);
    }
    int2 pk; pk.x = (int)lo; pk.y = (int)hi;
    *(int2*)(xq + (size_t)t * HD + tid * 8) = pk;
}

// ---------------- weight conversion int32 -> int8 ----------------
__global__ __launch_bounds__(256) void convert_w13_kernel(
    const int* __restrict__ wq, signed char* __restrict__ w8)
{
    const unsigned idx = blockIdx.x * 256u + threadIdx.x;
    const unsigned kq = idx & 511u;
    const unsigned rowq = idx >> 9;
    const unsigned np = rowq % 2816u;
    const unsigned e = rowq / 2816u;
    const unsigned inrow = ((np >> 4) & 1u) * 1408u + (np >> 5) * 16u + (np & 15u);
    const int4 vv = *(const int4*)(wq + (size_t)(e * 2816u + inrow) * 2048u + kq * 4u);
    char4 c;
    c.x = (signed char)vv.x; c.y = (signed char)vv.y;
    c.z = (signed char)vv.z; c.w = (signed char)vv.w;
    *(char4*)(w8 + (size_t)rowq * 2048u + kq * 4u) = c;
}

__global__ __launch_bounds__(256) void convert_w2_kernel(
    const int* __restrict__ wq, signed char* __restrict__ w8)
{
    const size_t idx = (size_t)blockIdx.x * 256 + threadIdx.x;
    const int4 vv = *(const int4*)(wq + idx * 4);
    char4 c;
    c.x = (signed char)vv.x; c.y = (signed char)vv.y;
    c.z = (signed char)vv.z; c.w = (signed char)vv.w;
    *(char4*)(w8 + idx * 4) = c;
}

// ---------------- out = shared_output ----------------
__global__ __launch_bounds__(256) void copy_out_kernel(
    const float* __restrict__ src, float* __restrict__ dst)
{
    const size_t idx = (size_t)blockIdx.x * 256 + threadIdx.x;
    ((float4*)dst)[idx] = ((const float4*)src)[idx];
}

// ---------------- fc1: grouped int8 GEMM + SwiGLU + row-absmax ----------------
// LDS layout (XOR swizzle): element (row, k16) at row*64 + (k16 ^ (row&3))*16.
// Staged via global_load_lds (wave-uniform base + lane*16): swizzle applied on
// the per-lane GLOBAL address, so LDS writes are sequential (conflict-free)
// and frag reads are perfectly bank-balanced (8 dwords/bank per wave b128).
__global__ __launch_bounds__(256, 2) void fc1_kernel(
    const signed char* __restrict__ xq, const signed char* __restrict__ w13_8,
    const float* __restrict__ xs, const float* __restrict__ w13s,
    const int* __restrict__ counts, const int* __restrict__ lists,
    __hip_bfloat16* __restrict__ a_buf, unsigned int* __restrict__ amax)
{
    const int e = blockIdx.z;
    const int n_e = counts[e];
    const int m0 = blockIdx.y * 128;
    if (m0 >= n_e) return;
    const int n0 = blockIdx.x * 128;
    const int* list = lists + e * TOKS;
    const signed char* B = w13_8 + (size_t)e * N13 * HD;

    __shared__ signed char lsA[128 * 64];
    __shared__ signed char lsB[128 * 64];

    const int tid = threadIdx.x;
    const int wv = tid >> 6;
    const int l  = tid & 63;
    const int r4 = l >> 2;            // row within 16-row group
    const int c4 = l & 3;             // k16 slot within row
    const int k16 = c4 ^ (r4 & 3);    // swizzled content index (same for both issues)

    // staging rows: issue j covers rows wv*32 + j*16 + r4
    const int rowA0 = m0 + wv * 32 + r4;
    const int rowA1 = rowA0 + 16;
    const int slotA0 = (rowA0 < n_e) ? list[rowA0] : 0;
    const int slotA1 = (rowA1 < n_e) ? list[rowA1] : 0;
    const signed char* gA0 = xq + (size_t)(slotA0 >> 1) * HD + k16 * 16;
    const signed char* gA1 = xq + (size_t)(slotA1 >> 1) * HD + k16 * 16;
    const signed char* gB0 = B + (size_t)(n0 + wv * 32 + r4) * HD + k16 * 16;
    const signed char* gB1 = gB0 + (size_t)16 * HD;
    signed char* ldsA0 = lsA + (wv * 2 + 0) * 1024;
    signed char* ldsA1 = lsA + (wv * 2 + 1) * 1024;
    signed char* ldsB0 = lsB + (wv * 2 + 0) * 1024;
    signed char* ldsB1 = lsB + (wv * 2 + 1) * 1024;

    const int quad = l >> 4, jj = l & 15;
    const int wm = (wv >> 1) * 64, wn = (wv & 1) * 64;
    const int swz = ((quad ^ (jj & 3)) * 16);

    const v4i zero = {0, 0, 0, 0};
    v4i acc[4][4];
#pragma unroll
    for (int a = 0; a < 4; ++a)
#pragma unroll
        for (int b = 0; b < 4; ++b) acc[a][b] = zero;

    for (int kc = 0; kc < 32; ++kc) {
        const int k0 = kc * 64;
        __syncthreads();
        async_copy16(gA0 + k0, ldsA0);
        async_copy16(gA1 + k0, ldsA1);
        async_copy16(gB0 + k0, ldsB0);
        async_copy16(gB1 + k0, ldsB1);
        __syncthreads();
        v4i af[4], bf[4];
#pragma unroll
        for (int mi = 0; mi < 4; ++mi)
            af[mi] = *(const v4i*)(lsA + (wm + mi * 16 + jj) * 64 + swz);
#pragma unroll
        for (int ni = 0; ni < 4; ++ni)
            bf[ni] = *(const v4i*)(lsB + (wn + ni * 16 + jj) * 64 + swz);
#pragma unroll
        for (int mi = 0; mi < 4; ++mi)
#pragma unroll
            for (int ni = 0; ni < 4; ++ni)
                acc[mi][ni] = __builtin_amdgcn_mfma_i32_16x16x64_i8(af[mi], bf[ni], acc[mi][ni], 0, 0, 0);
    }

    // epilogue: dequant, SwiGLU (pairs = adjacent ni tiles, same lane), bf16 a + absmax
    const float* s13e = w13s + e * N13;
    const int qbase = (n0 + wn) >> 5;
#pragma unroll
    for (int mi = 0; mi < 4; ++mi) {
#pragma unroll
        for (int r = 0; r < 4; ++r) {
            const int idx = m0 + wm + mi * 16 + quad * 4 + r;
            const bool valid = (idx < n_e);
            int slot = 0; float xsv = 0.f;
            if (valid) { slot = list[idx]; xsv = xs[slot >> 1]; }
            float rowmax = 0.f;
            float avals[2];
#pragma unroll
            for (int p = 0; p < 2; ++p) {
                const int q = qbase + p;
                const float sg = s13e[q * 16 + jj];
                const float su = s13e[ID + q * 16 + jj];
                const float hg = (float)acc[mi][2 * p][r] * xsv * sg;
                const float hu = (float)acc[mi][2 * p + 1][r] * xsv * su;
                const float av = hg / (1.0f + expf(-hg)) * hu;
                avals[p] = av;
                rowmax = fmaxf(rowmax, fabsf(av));
            }
            rowmax = fmaxf(rowmax, __shfl_xor(rowmax, 1));
            rowmax = fmaxf(rowmax, __shfl_xor(rowmax, 2));
            rowmax = fmaxf(rowmax, __shfl_xor(rowmax, 4));
            rowmax = fmaxf(rowmax, __shfl_xor(rowmax, 8));
            if (valid) {
                __hip_bfloat16* arow = a_buf + (size_t)slot * ID;
#pragma unroll
                for (int p = 0; p < 2; ++p)
                    arow[(qbase + p) * 16 + jj] = __float2bfloat16(avals[p]);
                if (jj == 0) atomicMax(amax + slot, __float_as_uint(rowmax));
            }
        }
    }
}

// ---------------- requant: a bf16 -> aq int8 with per-row scale ----------------
__global__ __launch_bounds__(192) void requant_kernel(
    const __hip_bfloat16* __restrict__ a_buf, const unsigned int* __restrict__ amax,
    float* __restrict__ a_s, signed char* __restrict__ aq)
{
    const int row = blockIdx.x;
    const float am = __uint_as_float(amax[row]);
    const float s = fmaxf(am / 127.0f, 1e-8f);
    if (threadIdx.x == 0) a_s[row] = s;
    const unsigned short* ar = (const unsigned short*)(a_buf + (size_t)row * ID);
    signed char* qr = aq + (size_t)row * ID;
    const float inv = 1.0f / s;
    for (int c = threadIdx.x; c < ID / 8; c += 192) {   // 176 chunks of 8
        union { int4 v; unsigned short u[8]; } dat;
        dat.v = *(const int4*)(ar + c * 8);
        unsigned int lo = 0, hi = 0;
#pragma unroll
        for (int i = 0; i < 4; ++i) {
            const float f = __uint_as_float((unsigned)dat.u[i] << 16);
            int q = (int)fminf(fmaxf(rintf(f * inv), -127.f), 127.f);
            lo |= ((unsigned)(q & 0xff)) << (8 * i);
        }
#pragma unroll
        for (int i = 0; i < 4; ++i) {
            const float f = __uint_as_float((unsigned)dat.u[4 + i] << 16);
            int q = (int)fminf(fmaxf(rintf(f * inv), -127.f), 127.f);
            hi |= ((unsigned)(q & 0xff)) << (8 * i);
        }
        int2 pk; pk.x = (int)lo; pk.y = (int)hi;
        *(int2*)(qr + c * 8) = pk;
    }
}

// ---------------- fc2: grouped int8 GEMM + weighted atomic combine ----------------
__global__ __launch_bounds__(256, 2) void fc2_kernel(
    const signed char* __restrict__ aq, const signed char* __restrict__ w2_8,
    const float* __restrict__ a_s, const float* __restrict__ w2s,
    const float* __restrict__ gates,
    const int* __restrict__ counts, const int* __restrict__ lists,
    float* __restrict__ out)
{
    const int e = blockIdx.z;
    const int n_e = counts[e];
    const int m0 = blockIdx.y * 128;
    if (m0 >= n_e) return;
    const int n0 = blockIdx.x * 128;
    const int* list = lists + e * TOKS;
    const signed char* B = w2_8 + (size_t)e * HD * ID;

    __shared__ signed char lsA[128 * 64];
    __shared__ signed char lsB[128 * 64];

    const int tid = threadIdx.x;
    const int wv = tid >> 6;
    const int l  = tid & 63;
    const int r4 = l >> 2;
    const int c4 = l & 3;
    const int k16 = c4 ^ (r4 & 3);

    const int rowA0 = m0 + wv * 32 + r4;
    const int rowA1 = rowA0 + 16;
    const int slotA0 = (rowA0 < n_e) ? list[rowA0] : 0;
    const int slotA1 = (rowA1 < n_e) ? list[rowA1] : 0;
    const signed char* gA0 = aq + (size_t)slotA0 * ID + k16 * 16;
    const signed char* gA1 = aq + (size_t)slotA1 * ID + k16 * 16;
    const signed char* gB0 = B + (size_t)(n0 + wv * 32 + r4) * ID + k16 * 16;
    const signed char* gB1 = gB0 + (size_t)16 * ID;
    signed char* ldsA0 = lsA + (wv * 2 + 0) * 1024;
    signed char* ldsA1 = lsA + (wv * 2 + 1) * 1024;
    signed char* ldsB0 = lsB + (wv * 2 + 0) * 1024;
    signed char* ldsB1 = lsB + (wv * 2 + 1) * 1024;

    const int quad = l >> 4, jj = l & 15;
    const int wm = (wv >> 1) * 64, wn = (wv & 1) * 64;
    const int swz = ((quad ^ (jj & 3)) * 16);

    const v4i zero = {0, 0, 0, 0};
    v4i acc[4][4];
#pragma unroll
    for (int a = 0; a < 4; ++a)
#pragma unroll
        for (int b = 0; b < 4; ++b) acc[a][b] = zero;

    for (int kc = 0; kc < 22; ++kc) {   // K = 1408
        const int k0 = kc * 64;
        __syncthreads();
        async_copy16(gA0 + k0, ldsA0);
        async_copy16(gA1 + k0, ldsA1);
        async_copy16(gB0 + k0, ldsB0);
        async_copy16(gB1 + k0, ldsB1);
        __syncthreads();
        v4i af[4], bf[4];
#pragma unroll
        for (int mi = 0; mi < 4; ++mi)
            af[mi] = *(const v4i*)(lsA + (wm + mi * 16 + jj) * 64 + swz);
#pragma unroll
        for (int ni = 0; ni < 4; ++ni)
            bf[ni] = *(const v4i*)(lsB + (wn + ni * 16 + jj) * 64 + swz);
#pragma unroll
        for (int mi = 0; mi < 4; ++mi)
#pragma unroll
            for (int ni = 0; ni < 4; ++ni)
                acc[mi][ni] = __builtin_amdgcn_mfma_i32_16x16x64_i8(af[mi], bf[ni], acc[mi][ni], 0, 0, 0);
    }

    const float* s2e = w2s + e * HD;
    float s2v[4];
#pragma unroll
    for (int ni = 0; ni < 4; ++ni) s2v[ni] = s2e[n0 + wn + ni * 16 + jj];
#pragma unroll
    for (int mi = 0; mi < 4; ++mi) {
#pragma unroll
        for (int r = 0; r < 4; ++r) {
            const int idx = m0 + wm + mi * 16 + quad * 4 + r;
            if (idx >= n_e) continue;
            const int slot = list[idx];
            const float coef = a_s[slot] * gates[slot];
            float* orow = out + (size_t)(slot >> 1) * HD + n0 + wn;
#pragma unroll
            for (int ni = 0; ni < 4; ++ni)
                atomicAdd(orow + ni * 16 + jj, (float)acc[mi][ni][r] * coef * s2v[ni]);
        }
    }
}

extern "C" void kernel_launch(void* const* d_in, const int* in_sizes, int n_in,
                              void* d_out, int out_size, void* d_ws, size_t ws_size,
                              hipStream_t stream)
{
    const float* x      = (const float*)d_in[0];
    const float* gw     = (const float*)d_in[1];
    const int*   w13q   = (const int*)d_in[2];
    const float* w13s   = (const float*)d_in[3];
    const int*   w2q    = (const int*)d_in[4];
    const float* w2s    = (const float*)d_in[5];
    const float* shared = (const float*)d_in[6];
    float* out = (float*)d_out;
    char* ws = (char*)d_ws;

    constexpr size_t SZ_W13 = (size_t)NE * N13 * HD;   // 46,137,344
    constexpr size_t SZ_W2  = (size_t)NE * HD * ID;    // 23,068,672
    constexpr size_t SZ_XQ  = (size_t)TOKS * HD;       // 16,777,216
    constexpr size_t SZ_AQ  = (size_t)2 * TOKS * ID;   // 23,068,672
    constexpr size_t SZ_A   = SZ_AQ * 2;               // bf16: 46,137,344
    constexpr size_t OFF_W13 = 0;
    constexpr size_t OFF_W2  = OFF_W13 + SZ_W13;
    constexpr size_t OFF_XQ  = OFF_W2 + SZ_W2;
    constexpr size_t OFF_AQ  = OFF_XQ + SZ_XQ;
    constexpr size_t OFF_A   = OFF_AQ + SZ_AQ;
    constexpr size_t OFF_XS  = OFF_A + SZ_A;
    constexpr size_t OFF_AS  = OFF_XS + 65536;
    constexpr size_t OFF_G   = OFF_AS + 65536;
    constexpr size_t OFF_AM  = OFF_G + 65536;
    constexpr size_t OFF_CNT = OFF_AM + 65536;
    constexpr size_t OFF_LST = OFF_CNT + 256;

    signed char* w13_8 = (signed char*)(ws + OFF_W13);
    signed char* w2_8  = (signed char*)(ws + OFF_W2);
    signed char* xq    = (signed char*)(ws + OFF_XQ);
    signed char* aqb   = (signed char*)(ws + OFF_AQ);
    __hip_bfloat16* a_buf = (__hip_bfloat16*)(ws + OFF_A);
    float* xs    = (float*)(ws + OFF_XS);
    float* a_s   = (float*)(ws + OFF_AS);
    float* gates = (float*)(ws + OFF_G);
    unsigned int* amax = (unsigned int*)(ws + OFF_AM);
    int* counts = (int*)(ws + OFF_CNT);
    int* lists  = (int*)(ws + OFF_LST);

    hipMemsetAsync(counts, 0, 256, stream);
    hipMemsetAsync(amax, 0, 65536, stream);

    gate_quant_kernel<<<TOKS, 256, 0, stream>>>(x, gw, xq, xs, gates, counts, lists);
    convert_w13_kernel<<<(NE * N13 * (HD / 4)) / 256, 256, 0, stream>>>(w13q, w13_8);
    convert_w2_kernel<<<(NE * HD * (ID / 4)) / 256, 256, 0, stream>>>(w2q, w2_8);
    copy_out_kernel<<<(TOKS * HD / 4) / 256, 256, 0, stream>>>(shared, out);
    fc1_kernel<<<dim3(N13 / 128, 64, NE), 256, 0, stream>>>(
        xq, w13_8, xs, w13s, counts, lists, a_buf, amax);
    requant_kernel<<<2 * TOKS, 192, 0, stream>>>(a_buf, amax, a_s, aqb);
    fc2_kernel<<<dim3(HD / 128, 64, NE), 256, 0, stream>>>(
        aqb, w2_8, a_s, w2s, gates, counts, lists, out);
}

// Round 3
// 818.897 us; speedup vs baseline: 1.1575x; 1.1245x over previous
//
#include <hip/hip_runtime.h>
#include <hip/hip_bf16.h>
#include <math.h>

#define TOKS 8192
#define HD   2048
#define ID   1408
#define NE   8
#define N13  2816

typedef int v4i __attribute__((ext_vector_type(4)));

__device__ __forceinline__ void async_copy16(const signed char* g, signed char* l) {
    __builtin_amdgcn_global_load_lds(
        (const __attribute__((address_space(1))) void*)g,
        (__attribute__((address_space(3))) void*)l, 16, 0, 0);
}

// ---------------- gating + dynamic x quant (no global atomics) ----------------
__global__ __launch_bounds__(256) void gate_quant_kernel(
    const float* __restrict__ x, const float* __restrict__ gw,
    signed char* __restrict__ xq, float* __restrict__ xs,
    float* __restrict__ gates, unsigned char* __restrict__ ex_of_slot)
{
    const int t = blockIdx.x;
    const int tid = threadIdx.x;
    const float* xr = x + (size_t)t * HD + tid * 8;
    const float4 xa = *(const float4*)(xr);
    const float4 xb = *(const float4*)(xr + 4);
    float acc[NE];
#pragma unroll
    for (int e = 0; e < NE; ++e) {
        const float* wr = gw + e * HD + tid * 8;
        float4 wa = *(const float4*)(wr);
        float4 wb = *(const float4*)(wr + 4);
        acc[e] = xa.x*wa.x + xa.y*wa.y + xa.z*wa.z + xa.w*wa.w +
                 xb.x*wb.x + xb.y*wb.y + xb.z*wb.z + xb.w*wb.w;
    }
    float am = fmaxf(fmaxf(fmaxf(fabsf(xa.x), fabsf(xa.y)), fmaxf(fabsf(xa.z), fabsf(xa.w))),
                     fmaxf(fmaxf(fabsf(xb.x), fabsf(xb.y)), fmaxf(fabsf(xb.z), fabsf(xb.w))));
#pragma unroll
    for (int off = 1; off < 64; off <<= 1) {
#pragma unroll
        for (int e = 0; e < NE; ++e) acc[e] += __shfl_xor(acc[e], off);
        am = fmaxf(am, __shfl_xor(am, off));
    }
    __shared__ float red[4][9];
    __shared__ float logit_s[8];
    __shared__ float sbc;
    const int wv = tid >> 6;
    if ((tid & 63) == 0) {
#pragma unroll
        for (int e = 0; e < NE; ++e) red[wv][e] = acc[e];
        red[wv][8] = am;
    }
    __syncthreads();
    if (tid < 8) logit_s[tid] = red[0][tid] + red[1][tid] + red[2][tid] + red[3][tid];
    if (tid == 8) {
        const float amx = fmaxf(fmaxf(red[0][8], red[1][8]), fmaxf(red[2][8], red[3][8]));
        const float s = fmaxf(amx / 127.0f, 1e-8f);
        xs[t] = s;
        sbc = s;
    }
    __syncthreads();
    if (tid == 0) {
        float l[NE];
#pragma unroll
        for (int e = 0; e < NE; ++e) l[e] = logit_s[e];
        int e0 = 0;
#pragma unroll
        for (int e = 1; e < NE; ++e) if (l[e] > l[e0]) e0 = e;
        int e1 = (e0 == 0) ? 1 : 0;
#pragma unroll
        for (int e = 0; e < NE; ++e) if (e != e0 && l[e] > l[e1]) e1 = e;
        const float d = expf(l[e1] - l[e0]);
        gates[2*t]     = 1.0f / (1.0f + d);
        gates[2*t + 1] = d / (1.0f + d);
        uchar2 p; p.x = (unsigned char)e0; p.y = (unsigned char)e1;
        *(uchar2*)(ex_of_slot + 2 * t) = p;
    }
    const float s = sbc;
    const float v[8] = {xa.x, xa.y, xa.z, xa.w, xb.x, xb.y, xb.z, xb.w};
    unsigned int lo = 0, hi = 0;
#pragma unroll
    for (int i = 0; i < 4; ++i) {
        int q = (int)fminf(fmaxf(rintf(v[i] / s), -127.f), 127.f);
        lo |= ((unsigned)(q & 0xff)) << (8 * i);
    }
#pragma unroll
    for (int i = 0; i < 4; ++i) {
        int q = (int)fminf(fmaxf(rintf(v[4 + i] / s), -127.f), 127.f);
        hi |= ((unsigned)(q & 0xff)) << (8 * i);
    }
    int2 pk; pk.x = (int)lo; pk.y = (int)hi;
    *(int2*)(xq + (size_t)t * HD + tid * 8) = pk;
}

// ---------------- build per-expert token lists (ballot compaction) ----------------
__global__ __launch_bounds__(256) void build_lists_kernel(
    const unsigned char* __restrict__ ex_of_slot,
    int* __restrict__ counts, int* __restrict__ lists)
{
    const int e = blockIdx.x;
    const int tid = threadIdx.x;
    const int lane = tid & 63;
    const int wv = tid >> 6;
    __shared__ int wsum[4];
    __shared__ int base;
    if (tid == 0) base = 0;
    __syncthreads();
    int* mylist = lists + e * TOKS;
    for (int it = 0; it < 2 * TOKS / 256; ++it) {
        const int slot = it * 256 + tid;
        const bool m = (ex_of_slot[slot] == (unsigned char)e);
        const unsigned long long mask = __ballot(m);
        const int wprefix = __popcll(mask & ((1ULL << lane) - 1ULL));
        if (lane == 0) wsum[wv] = __popcll(mask);
        __syncthreads();
        int wbase = base;
        for (int w = 0; w < wv; ++w) wbase += wsum[w];
        if (m) mylist[wbase + wprefix] = slot;
        __syncthreads();
        if (tid == 0) base += wsum[0] + wsum[1] + wsum[2] + wsum[3];
        __syncthreads();
    }
    if (tid == 0) counts[e] = base;
}

// ---------------- weight conversion int32 -> int8 ----------------
__global__ __launch_bounds__(256) void convert_w13_kernel(
    const int* __restrict__ wq, signed char* __restrict__ w8)
{
    const unsigned idx = blockIdx.x * 256u + threadIdx.x;
    const unsigned kq = idx & 511u;
    const unsigned rowq = idx >> 9;
    const unsigned np = rowq % 2816u;
    const unsigned e = rowq / 2816u;
    const unsigned inrow = ((np >> 4) & 1u) * 1408u + (np >> 5) * 16u + (np & 15u);
    const int4 vv = *(const int4*)(wq + (size_t)(e * 2816u + inrow) * 2048u + kq * 4u);
    char4 c;
    c.x = (signed char)vv.x; c.y = (signed char)vv.y;
    c.z = (signed char)vv.z; c.w = (signed char)vv.w;
    *(char4*)(w8 + (size_t)rowq * 2048u + kq * 4u) = c;
}

__global__ __launch_bounds__(256) void convert_w2_kernel(
    const int* __restrict__ wq, signed char* __restrict__ w8)
{
    const size_t idx = (size_t)blockIdx.x * 256 + threadIdx.x;
    const int4 vv = *(const int4*)(wq + idx * 4);
    char4 c;
    c.x = (signed char)vv.x; c.y = (signed char)vv.y;
    c.z = (signed char)vv.z; c.w = (signed char)vv.w;
    *(char4*)(w8 + idx * 4) = c;
}

// ---------------- out = shared_output ----------------
__global__ __launch_bounds__(256) void copy_out_kernel(
    const float* __restrict__ src, float* __restrict__ dst)
{
    const size_t idx = (size_t)blockIdx.x * 256 + threadIdx.x;
    ((float4*)dst)[idx] = ((const float4*)src)[idx];
}

// ---------------- fc1: grouped int8 GEMM + SwiGLU + row-absmax ----------------
__global__ __launch_bounds__(256, 2) void fc1_kernel(
    const signed char* __restrict__ xq, const signed char* __restrict__ w13_8,
    const float* __restrict__ xs, const float* __restrict__ w13s,
    const int* __restrict__ counts, const int* __restrict__ lists,
    __hip_bfloat16* __restrict__ a_buf, unsigned int* __restrict__ amax)
{
    const int e = blockIdx.z;
    const int n_e = counts[e];
    const int m0 = blockIdx.y * 128;
    if (m0 >= n_e) return;
    const int n0 = blockIdx.x * 128;
    const int* list = lists + e * TOKS;
    const signed char* B = w13_8 + (size_t)e * N13 * HD;

    __shared__ signed char lsA[128 * 64];
    __shared__ signed char lsB[128 * 64];

    const int tid = threadIdx.x;
    const int wv = tid >> 6;
    const int l  = tid & 63;
    const int r4 = l >> 2;
    const int c4 = l & 3;
    const int k16 = c4 ^ (r4 & 3);

    const int rowA0 = m0 + wv * 32 + r4;
    const int rowA1 = rowA0 + 16;
    const int slotA0 = (rowA0 < n_e) ? list[rowA0] : 0;
    const int slotA1 = (rowA1 < n_e) ? list[rowA1] : 0;
    const signed char* gA0 = xq + (size_t)(slotA0 >> 1) * HD + k16 * 16;
    const signed char* gA1 = xq + (size_t)(slotA1 >> 1) * HD + k16 * 16;
    const signed char* gB0 = B + (size_t)(n0 + wv * 32 + r4) * HD + k16 * 16;
    const signed char* gB1 = gB0 + (size_t)16 * HD;
    signed char* ldsA0 = lsA + (wv * 2 + 0) * 1024;
    signed char* ldsA1 = lsA + (wv * 2 + 1) * 1024;
    signed char* ldsB0 = lsB + (wv * 2 + 0) * 1024;
    signed char* ldsB1 = lsB + (wv * 2 + 1) * 1024;

    const int quad = l >> 4, jj = l & 15;
    const int wm = (wv >> 1) * 64, wn = (wv & 1) * 64;
    const int swz = ((quad ^ (jj & 3)) * 16);

    const v4i zero = {0, 0, 0, 0};
    v4i acc[4][4];
#pragma unroll
    for (int a = 0; a < 4; ++a)
#pragma unroll
        for (int b = 0; b < 4; ++b) acc[a][b] = zero;

    for (int kc = 0; kc < 32; ++kc) {
        const int k0 = kc * 64;
        __syncthreads();
        async_copy16(gA0 + k0, ldsA0);
        async_copy16(gA1 + k0, ldsA1);
        async_copy16(gB0 + k0, ldsB0);
        async_copy16(gB1 + k0, ldsB1);
        __syncthreads();
        v4i af[4], bf[4];
#pragma unroll
        for (int mi = 0; mi < 4; ++mi)
            af[mi] = *(const v4i*)(lsA + (wm + mi * 16 + jj) * 64 + swz);
#pragma unroll
        for (int ni = 0; ni < 4; ++ni)
            bf[ni] = *(const v4i*)(lsB + (wn + ni * 16 + jj) * 64 + swz);
#pragma unroll
        for (int mi = 0; mi < 4; ++mi)
#pragma unroll
            for (int ni = 0; ni < 4; ++ni)
                acc[mi][ni] = __builtin_amdgcn_mfma_i32_16x16x64_i8(af[mi], bf[ni], acc[mi][ni], 0, 0, 0);
    }

    const float* s13e = w13s + e * N13;
    const int qbase = (n0 + wn) >> 5;
#pragma unroll
    for (int mi = 0; mi < 4; ++mi) {
#pragma unroll
        for (int r = 0; r < 4; ++r) {
            const int idx = m0 + wm + mi * 16 + quad * 4 + r;
            const bool valid = (idx < n_e);
            int slot = 0; float xsv = 0.f;
            if (valid) { slot = list[idx]; xsv = xs[slot >> 1]; }
            float rowmax = 0.f;
            float avals[2];
#pragma unroll
            for (int p = 0; p < 2; ++p) {
                const int q = qbase + p;
                const float sg = s13e[q * 16 + jj];
                const float su = s13e[ID + q * 16 + jj];
                const float hg = (float)acc[mi][2 * p][r] * xsv * sg;
                const float hu = (float)acc[mi][2 * p + 1][r] * xsv * su;
                const float av = hg / (1.0f + expf(-hg)) * hu;
                avals[p] = av;
                rowmax = fmaxf(rowmax, fabsf(av));
            }
            rowmax = fmaxf(rowmax, __shfl_xor(rowmax, 1));
            rowmax = fmaxf(rowmax, __shfl_xor(rowmax, 2));
            rowmax = fmaxf(rowmax, __shfl_xor(rowmax, 4));
            rowmax = fmaxf(rowmax, __shfl_xor(rowmax, 8));
            if (valid) {
                __hip_bfloat16* arow = a_buf + (size_t)slot * ID;
#pragma unroll
                for (int p = 0; p < 2; ++p)
                    arow[(qbase + p) * 16 + jj] = __float2bfloat16(avals[p]);
                if (jj == 0) atomicMax(amax + slot, __float_as_uint(rowmax));
            }
        }
    }
}

// ---------------- requant: a bf16 -> aq int8 with per-row scale ----------------
__global__ __launch_bounds__(192) void requant_kernel(
    const __hip_bfloat16* __restrict__ a_buf, const unsigned int* __restrict__ amax,
    float* __restrict__ a_s, signed char* __restrict__ aq)
{
    const int row = blockIdx.x;
    const float am = __uint_as_float(amax[row]);
    const float s = fmaxf(am / 127.0f, 1e-8f);
    if (threadIdx.x == 0) a_s[row] = s;
    const unsigned short* ar = (const unsigned short*)(a_buf + (size_t)row * ID);
    signed char* qr = aq + (size_t)row * ID;
    const float inv = 1.0f / s;
    for (int c = threadIdx.x; c < ID / 8; c += 192) {
        union { int4 v; unsigned short u[8]; } dat;
        dat.v = *(const int4*)(ar + c * 8);
        unsigned int lo = 0, hi = 0;
#pragma unroll
        for (int i = 0; i < 4; ++i) {
            const float f = __uint_as_float((unsigned)dat.u[i] << 16);
            int q = (int)fminf(fmaxf(rintf(f * inv), -127.f), 127.f);
            lo |= ((unsigned)(q & 0xff)) << (8 * i);
        }
#pragma unroll
        for (int i = 0; i < 4; ++i) {
            const float f = __uint_as_float((unsigned)dat.u[4 + i] << 16);
            int q = (int)fminf(fmaxf(rintf(f * inv), -127.f), 127.f);
            hi |= ((unsigned)(q & 0xff)) << (8 * i);
        }
        int2 pk; pk.x = (int)lo; pk.y = (int)hi;
        *(int2*)(qr + c * 8) = pk;
    }
}

// ---------------- fc2: grouped int8 GEMM + weighted atomic combine ----------------
__global__ __launch_bounds__(256, 2) void fc2_kernel(
    const signed char* __restrict__ aq, const signed char* __restrict__ w2_8,
    const float* __restrict__ a_s, const float* __restrict__ w2s,
    const float* __restrict__ gates,
    const int* __restrict__ counts, const int* __restrict__ lists,
    float* __restrict__ out)
{
    const int e = blockIdx.z;
    const int n_e = counts[e];
    const int m0 = blockIdx.y * 128;
    if (m0 >= n_e) return;
    const int n0 = blockIdx.x * 128;
    const int* list = lists + e * TOKS;
    const signed char* B = w2_8 + (size_t)e * HD * ID;

    __shared__ signed char lsA[128 * 64];
    __shared__ signed char lsB[128 * 64];

    const int tid = threadIdx.x;
    const int wv = tid >> 6;
    const int l  = tid & 63;
    const int r4 = l >> 2;
    const int c4 = l & 3;
    const int k16 = c4 ^ (r4 & 3);

    const int rowA0 = m0 + wv * 32 + r4;
    const int rowA1 = rowA0 + 16;
    const int slotA0 = (rowA0 < n_e) ? list[rowA0] : 0;
    const int slotA1 = (rowA1 < n_e) ? list[rowA1] : 0;
    const signed char* gA0 = aq + (size_t)slotA0 * ID + k16 * 16;
    const signed char* gA1 = aq + (size_t)slotA1 * ID + k16 * 16;
    const signed char* gB0 = B + (size_t)(n0 + wv * 32 + r4) * ID + k16 * 16;
    const signed char* gB1 = gB0 + (size_t)16 * ID;
    signed char* ldsA0 = lsA + (wv * 2 + 0) * 1024;
    signed char* ldsA1 = lsA + (wv * 2 + 1) * 1024;
    signed char* ldsB0 = lsB + (wv * 2 + 0) * 1024;
    signed char* ldsB1 = lsB + (wv * 2 + 1) * 1024;

    const int quad = l >> 4, jj = l & 15;
    const int wm = (wv >> 1) * 64, wn = (wv & 1) * 64;
    const int swz = ((quad ^ (jj & 3)) * 16);

    const v4i zero = {0, 0, 0, 0};
    v4i acc[4][4];
#pragma unroll
    for (int a = 0; a < 4; ++a)
#pragma unroll
        for (int b = 0; b < 4; ++b) acc[a][b] = zero;

    for (int kc = 0; kc < 22; ++kc) {
        const int k0 = kc * 64;
        __syncthreads();
        async_copy16(gA0 + k0, ldsA0);
        async_copy16(gA1 + k0, ldsA1);
        async_copy16(gB0 + k0, ldsB0);
        async_copy16(gB1 + k0, ldsB1);
        __syncthreads();
        v4i af[4], bf[4];
#pragma unroll
        for (int mi = 0; mi < 4; ++mi)
            af[mi] = *(const v4i*)(lsA + (wm + mi * 16 + jj) * 64 + swz);
#pragma unroll
        for (int ni = 0; ni < 4; ++ni)
            bf[ni] = *(const v4i*)(lsB + (wn + ni * 16 + jj) * 64 + swz);
#pragma unroll
        for (int mi = 0; mi < 4; ++mi)
#pragma unroll
            for (int ni = 0; ni < 4; ++ni)
                acc[mi][ni] = __builtin_amdgcn_mfma_i32_16x16x64_i8(af[mi], bf[ni], acc[mi][ni], 0, 0, 0);
    }

    const float* s2e = w2s + e * HD;
    float s2v[4];
#pragma unroll
    for (int ni = 0; ni < 4; ++ni) s2v[ni] = s2e[n0 + wn + ni * 16 + jj];
#pragma unroll
    for (int mi = 0; mi < 4; ++mi) {
#pragma unroll
        for (int r = 0; r < 4; ++r) {
            const int idx = m0 + wm + mi * 16 + quad * 4 + r;
            if (idx >= n_e) continue;
            const int slot = list[idx];
            const float coef = a_s[slot] * gates[slot];
            float* orow = out + (size_t)(slot >> 1) * HD + n0 + wn;
#pragma unroll
            for (int ni = 0; ni < 4; ++ni)
                atomicAdd(orow + ni * 16 + jj, (float)acc[mi][ni][r] * coef * s2v[ni]);
        }
    }
}

extern "C" void kernel_launch(void* const* d_in, const int* in_sizes, int n_in,
                              void* d_out, int out_size, void* d_ws, size_t ws_size,
                              hipStream_t stream)
{
    const float* x      = (const float*)d_in[0];
    const float* gw     = (const float*)d_in[1];
    const int*   w13q   = (const int*)d_in[2];
    const float* w13s   = (const float*)d_in[3];
    const int*   w2q    = (const int*)d_in[4];
    const float* w2s    = (const float*)d_in[5];
    const float* shared = (const float*)d_in[6];
    float* out = (float*)d_out;
    char* ws = (char*)d_ws;

    constexpr size_t SZ_W13 = (size_t)NE * N13 * HD;
    constexpr size_t SZ_W2  = (size_t)NE * HD * ID;
    constexpr size_t SZ_XQ  = (size_t)TOKS * HD;
    constexpr size_t SZ_AQ  = (size_t)2 * TOKS * ID;
    constexpr size_t SZ_A   = SZ_AQ * 2;               // bf16
    constexpr size_t OFF_W13 = 0;
    constexpr size_t OFF_W2  = OFF_W13 + SZ_W13;
    constexpr size_t OFF_XQ  = OFF_W2 + SZ_W2;
    constexpr size_t OFF_AQ  = OFF_XQ + SZ_XQ;
    constexpr size_t OFF_A   = OFF_AQ + SZ_AQ;
    constexpr size_t OFF_XS  = OFF_A + SZ_A;
    constexpr size_t OFF_AS  = OFF_XS + 65536;
    constexpr size_t OFF_G   = OFF_AS + 65536;
    constexpr size_t OFF_AM  = OFF_G + 65536;
    constexpr size_t OFF_EX  = OFF_AM + 65536;          // 16384 bytes
    constexpr size_t OFF_CNT = OFF_EX + 16384;
    constexpr size_t OFF_LST = OFF_CNT + 256;

    signed char* w13_8 = (signed char*)(ws + OFF_W13);
    signed char* w2_8  = (signed char*)(ws + OFF_W2);
    signed char* xq    = (signed char*)(ws + OFF_XQ);
    signed char* aqb   = (signed char*)(ws + OFF_AQ);
    __hip_bfloat16* a_buf = (__hip_bfloat16*)(ws + OFF_A);
    float* xs    = (float*)(ws + OFF_XS);
    float* a_s   = (float*)(ws + OFF_AS);
    float* gates = (float*)(ws + OFF_G);
    unsigned int* amax = (unsigned int*)(ws + OFF_AM);
    unsigned char* ex_of_slot = (unsigned char*)(ws + OFF_EX);
    int* counts = (int*)(ws + OFF_CNT);
    int* lists  = (int*)(ws + OFF_LST);

    hipMemsetAsync(amax, 0, 65536, stream);

    gate_quant_kernel<<<TOKS, 256, 0, stream>>>(x, gw, xq, xs, gates, ex_of_slot);
    build_lists_kernel<<<NE, 256, 0, stream>>>(ex_of_slot, counts, lists);
    convert_w13_kernel<<<(NE * N13 * (HD / 4)) / 256, 256, 0, stream>>>(w13q, w13_8);
    convert_w2_kernel<<<(NE * HD * (ID / 4)) / 256, 256, 0, stream>>>(w2q, w2_8);
    copy_out_kernel<<<(TOKS * HD / 4) / 256, 256, 0, stream>>>(shared, out);
    fc1_kernel<<<dim3(N13 / 128, 64, NE), 256, 0, stream>>>(
        xq, w13_8, xs, w13s, counts, lists, a_buf, amax);
    requant_kernel<<<2 * TOKS, 192, 0, stream>>>(a_buf, amax, a_s, aqb);
    fc2_kernel<<<dim3(HD / 128, 64, NE), 256, 0, stream>>>(
        aqb, w2_8, a_s, w2s, gates, counts, lists, out);
}